// Round 1
// baseline (158.343 us; speedup 1.0000x reference)
//
#include <hip/hip_runtime.h>
#include <math.h>

#define H      128
#define NLAYER 3
#define FCN    400
#define L1N    500
#define L2N    63
#define STEPS  65536

__device__ __forceinline__ float sigmoidf_(float v) {
    return 1.0f / (1.0f + expf(-v));
}

// dot of a global row (16B-aligned, K multiple of 4) with an LDS vector
__device__ __forceinline__ float dot_row(const float* __restrict__ w,
                                         const float* __restrict__ x, int K) {
    const float4* w4 = (const float4*)w;
    const float4* x4 = (const float4*)x;
    float ax = 0.f, ay = 0.f, az = 0.f, aw = 0.f;
#pragma unroll 4
    for (int k = 0; k < (K >> 2); ++k) {
        float4 a = w4[k];
        float4 b = x4[k];
        ax = fmaf(a.x, b.x, ax);
        ay = fmaf(a.y, b.y, ay);
        az = fmaf(a.z, b.z, az);
        aw = fmaf(a.w, b.w, aw);
    }
    return (ax + ay) + (az + aw);
}

__global__ __launch_bounds__(512) void rnn_last_step_kernel(
    const float* __restrict__ inputs,  // [STEPS, H]
    const float* __restrict__ W_ih,    // [L, 4H, H]
    const float* __restrict__ b_ih,    // [L, 4H]
    const float* __restrict__ b_hh,    // [L, 4H]
    const float* __restrict__ W_fc,    // [FCN, H]
    const float* __restrict__ b_fc,    // [FCN]
    const float* __restrict__ W_l1,    // [L1N, FCN]
    const float* __restrict__ b_l1,    // [L1N]
    const float* __restrict__ W_l2,    // [L2N, L1N]
    const float* __restrict__ b_l2,    // [L2N]
    float* __restrict__ out)           // [L2N]
{
    __shared__ __align__(16) float s_a[512];  // x / h / l1 activations
    __shared__ __align__(16) float s_b[512];  // gates / fc activations

    const int tid = threadIdx.x;

    // stage 0: load last input row
    if (tid < H) s_a[tid] = inputs[(size_t)(STEPS - 1) * H + tid];
    __syncthreads();

    // 3 LSTM-cell layers with h0=c0=0: only i, g, o gates matter
    for (int l = 0; l < NLAYER; ++l) {
        if (tid < 3 * H) {
            const int q = tid >> 7;           // 0 -> i, 1 -> g, 2 -> o
            const int r = tid & (H - 1);
            const int grow = (q == 0) ? 0 : (q == 1 ? 2 : 3);  // gate order i,f,g,o
            const int row = (l * 4 + grow) * H + r;            // row index into [L*4H]
            float d = dot_row(W_ih + (size_t)row * H, s_a, H);
            d += b_ih[row] + b_hh[row];
            s_b[tid] = d;
        }
        __syncthreads();
        if (tid < H) {
            float ig = s_b[tid];
            float gg = s_b[H + tid];
            float og = s_b[2 * H + tid];
            float c  = sigmoidf_(ig) * tanhf(gg);
            s_a[tid] = sigmoidf_(og) * tanhf(c);
        }
        __syncthreads();
    }

    // FC: [FCN, H] @ s_a[H]
    if (tid < FCN) {
        s_b[tid] = dot_row(W_fc + (size_t)tid * H, s_a, H) + b_fc[tid];
    }
    __syncthreads();

    // L1: [L1N, FCN] @ s_b[FCN]
    if (tid < L1N) {
        s_a[tid] = dot_row(W_l1 + (size_t)tid * FCN, s_b, FCN) + b_l1[tid];
    }
    __syncthreads();

    // L2: [L2N, L1N] @ s_a[L1N]
    if (tid < L2N) {
        out[tid] = dot_row(W_l2 + (size_t)tid * L1N, s_a, L1N) + b_l2[tid];
    }
}

extern "C" void kernel_launch(void* const* d_in, const int* in_sizes, int n_in,
                              void* d_out, int out_size, void* d_ws, size_t ws_size,
                              hipStream_t stream) {
    const float* inputs = (const float*)d_in[0];
    const float* W_ih   = (const float*)d_in[1];
    // d_in[2] = W_hh (unused: h0 = 0)
    const float* b_ih   = (const float*)d_in[3];
    const float* b_hh   = (const float*)d_in[4];
    const float* W_fc   = (const float*)d_in[5];
    const float* b_fc   = (const float*)d_in[6];
    const float* W_l1   = (const float*)d_in[7];
    const float* b_l1   = (const float*)d_in[8];
    const float* W_l2   = (const float*)d_in[9];
    const float* b_l2   = (const float*)d_in[10];
    float* out = (float*)d_out;

    rnn_last_step_kernel<<<1, 512, 0, stream>>>(
        inputs, W_ih, b_ih, b_hh, W_fc, b_fc, W_l1, b_l1, W_l2, b_l2, out);
}

// Round 2
// 107.095 us; speedup vs baseline: 1.4785x; 1.4785x over previous
//
#include <hip/hip_runtime.h>
#include <math.h>

#define H      128
#define FCN    400
#define L1N    500
#define L2N    63
#define STEPS  65536

__device__ __forceinline__ float sigmoidf_(float v) {
    return 1.0f / (1.0f + expf(-v));
}

__device__ __forceinline__ float wave_reduce(float v) {
#pragma unroll
    for (int off = 32; off > 0; off >>= 1)
        v += __shfl_down(v, off, 64);
    return v;
}

// One wave per h-element r (128 waves). Each wave computes the i,g,o gate
// dots (K=128, float2 per lane) and the fused activation. h0=c0=0 -> f gate
// irrelevant, W_hh contributes nothing.
__global__ __launch_bounds__(256) void lstm_kernel(
    const float* __restrict__ x,     // [H]
    const float* __restrict__ W_ih,  // [4H, H] (this layer)
    const float* __restrict__ b_ih,  // [4H]
    const float* __restrict__ b_hh,  // [4H]
    float* __restrict__ h)           // [H]
{
    const int lane = threadIdx.x & 63;
    const int wid  = (blockIdx.x << 2) | (threadIdx.x >> 6);  // 0..127

    const float2 xv = ((const float2*)x)[lane];
    const float2* wi = (const float2*)(W_ih + (size_t)(0 * H + wid) * H);
    const float2* wg = (const float2*)(W_ih + (size_t)(2 * H + wid) * H);
    const float2* wo = (const float2*)(W_ih + (size_t)(3 * H + wid) * H);
    const float2 a = wi[lane];
    const float2 b = wg[lane];
    const float2 c = wo[lane];

    float pi = fmaf(a.x, xv.x, a.y * xv.y);
    float pg = fmaf(b.x, xv.x, b.y * xv.y);
    float po = fmaf(c.x, xv.x, c.y * xv.y);
    pi = wave_reduce(pi);
    pg = wave_reduce(pg);
    po = wave_reduce(po);

    if (lane == 0) {
        const float ig = pi + b_ih[0 * H + wid] + b_hh[0 * H + wid];
        const float gg = pg + b_ih[2 * H + wid] + b_hh[2 * H + wid];
        const float og = po + b_ih[3 * H + wid] + b_hh[3 * H + wid];
        const float cc = sigmoidf_(ig) * tanhf(gg);
        h[wid] = sigmoidf_(og) * tanhf(cc);
    }
}

// One wave per output row, K == 128 (float2 per lane covers it exactly).
__global__ __launch_bounds__(256) void matvec128_kernel(
    const float* __restrict__ x,   // [128]
    const float* __restrict__ W,   // [N, 128]
    const float* __restrict__ b,   // [N]
    float* __restrict__ y,         // [N]
    int N)
{
    const int lane = threadIdx.x & 63;
    const int wid  = (blockIdx.x << 2) | (threadIdx.x >> 6);
    if (wid >= N) return;

    const float2 xv = ((const float2*)x)[lane];
    const float2 wv = ((const float2*)(W + (size_t)wid * H))[lane];
    float p = fmaf(wv.x, xv.x, wv.y * xv.y);
    p = wave_reduce(p);
    if (lane == 0) y[wid] = p + b[wid];
}

// One wave per output row, arbitrary K (multiple of 4), float4 strided loop.
__global__ __launch_bounds__(256) void matvec_kernel(
    const float* __restrict__ x,   // [K]
    const float* __restrict__ W,   // [N, K]
    const float* __restrict__ b,   // [N]
    float* __restrict__ y,         // [N]
    int N, int K)
{
    const int lane = threadIdx.x & 63;
    const int wid  = (blockIdx.x << 2) | (threadIdx.x >> 6);
    if (wid >= N) return;

    const float4* x4 = (const float4*)x;
    const float4* w4 = (const float4*)(W + (size_t)wid * K);
    const int K4 = K >> 2;
    float acc = 0.f;
    for (int k = lane; k < K4; k += 64) {
        const float4 a = w4[k];
        const float4 v = x4[k];
        acc = fmaf(a.x, v.x, acc);
        acc = fmaf(a.y, v.y, acc);
        acc = fmaf(a.z, v.z, acc);
        acc = fmaf(a.w, v.w, acc);
    }
    acc = wave_reduce(acc);
    if (lane == 0) y[wid] = acc + b[wid];
}

extern "C" void kernel_launch(void* const* d_in, const int* in_sizes, int n_in,
                              void* d_out, int out_size, void* d_ws, size_t ws_size,
                              hipStream_t stream) {
    const float* inputs = (const float*)d_in[0];
    const float* W_ih   = (const float*)d_in[1];
    // d_in[2] = W_hh (unused: h0 = 0)
    const float* b_ih   = (const float*)d_in[3];
    const float* b_hh   = (const float*)d_in[4];
    const float* W_fc   = (const float*)d_in[5];
    const float* b_fc   = (const float*)d_in[6];
    const float* W_l1   = (const float*)d_in[7];
    const float* b_l1   = (const float*)d_in[8];
    const float* W_l2   = (const float*)d_in[9];
    const float* b_l2   = (const float*)d_in[10];
    float* out = (float*)d_out;

    float* ws   = (float*)d_ws;
    float* h0   = ws + 0;      // 128
    float* h1   = ws + 128;    // 128
    float* h2   = ws + 256;    // 128
    float* fc_o = ws + 512;    // 400
    float* l1_o = ws + 1024;   // 500

    const float* x_last = inputs + (size_t)(STEPS - 1) * H;

    // 3 LSTM layers: 128 waves = 32 blocks x 256
    lstm_kernel<<<32, 256, 0, stream>>>(x_last, W_ih + 0 * 4 * H * H,
                                        b_ih + 0 * 4 * H, b_hh + 0 * 4 * H, h0);
    lstm_kernel<<<32, 256, 0, stream>>>(h0, W_ih + 1 * 4 * H * H,
                                        b_ih + 1 * 4 * H, b_hh + 1 * 4 * H, h1);
    lstm_kernel<<<32, 256, 0, stream>>>(h1, W_ih + 2 * 4 * H * H,
                                        b_ih + 2 * 4 * H, b_hh + 2 * 4 * H, h2);

    // FC: 400 rows, K=128 -> 100 blocks
    matvec128_kernel<<<100, 256, 0, stream>>>(h2, W_fc, b_fc, fc_o, FCN);

    // L1: 500 rows, K=400 -> 125 blocks
    matvec_kernel<<<125, 256, 0, stream>>>(fc_o, W_l1, b_l1, l1_o, L1N, FCN);

    // L2: 63 rows, K=500 -> 16 blocks
    matvec_kernel<<<16, 256, 0, stream>>>(l1_o, W_l2, b_l2, out, L2N, L1N);
}